// Round 4
// baseline (96.991 us; speedup 1.0000x reference)
//
#include <hip/hip_runtime.h>
#include <math.h>

#define BB   1024            // batch rows
#define FF   1024            // real features (row FF of weights = bias row)
#define NOUT 512             // [0,256)=eroded, [256,512)=dilated
#define NW   256             // cols per weight matrix
#define BT   128             // rows per block tile
#define CT   128             // cols per block tile
#define KS   16              // K-split planes
#define KT   (FF / KS)       // 64 f per block
#define XT_OFF ((size_t)KS * BB * NOUT)   // float offset of x^T inside ws

// ---- 64x64 tile transpose: x[r][f] -> xt[f][r] (both 1024x1024) ----
__global__ __launch_bounds__(256) void trop_transpose(
    const float* __restrict__ x, float* __restrict__ xt)
{
    __shared__ float t[64][65];
    const int f0 = blockIdx.x * 64;
    const int r0 = blockIdx.y * 64;
    const int tr = threadIdx.x >> 4;    // 0..15
    const int tc = threadIdx.x & 15;    // 0..15
#pragma unroll
    for (int q = 0; q < 4; ++q) {
        const int r = tr + q * 16;
        const float4 v = *(const float4*)(x + (size_t)(r0 + r) * FF + f0 + tc * 4);
        t[r][tc * 4 + 0] = v.x; t[r][tc * 4 + 1] = v.y;
        t[r][tc * 4 + 2] = v.z; t[r][tc * 4 + 3] = v.w;
    }
    __syncthreads();
#pragma unroll
    for (int q = 0; q < 4; ++q) {
        const int f = tr + q * 16;
        float4 v;
        v.x = t[tc * 4 + 0][f]; v.y = t[tc * 4 + 1][f];
        v.z = t[tc * 4 + 2][f]; v.w = t[tc * 4 + 3][f];
        *(float4*)(xt + (size_t)(f0 + f) * BB + r0 + tc * 4) = v;
    }
}

// ---- main: no LDS, no barriers; per-f direct global reads (L2-resident) ----
// Block = 256 threads: rg=tid>>4 (16 x 8 rows), cg=tid&15 (16 x (4+4) cols).
// Accumulates max-form partial for its f-slice; stores raw to ws plane bz.
__global__ __launch_bounds__(256, 2) void trop_main(
    const float* __restrict__ xt,
    const float* __restrict__ dil,
    const float* __restrict__ ero,
    float* __restrict__ ws)
{
    const int bx = blockIdx.x;            // 0,1: erosion tiles; 2,3: dilation
    const int by = blockIdx.y;            // 0..7 row tile
    const int bz = blockIdx.z;            // 0..KS-1 f slice
    const bool is_ero = (bx < 2);
    const float* __restrict__ w = is_ero ? ero : dil;
    const int c0w = (bx & 1) * CT;
    const int r0 = by * BT;

    const int tid = threadIdx.x;
    const int cg = tid & 15;
    const int rg = tid >> 4;

    float acc[8][8];
#pragma unroll
    for (int i = 0; i < 8; ++i)
#pragma unroll
        for (int j = 0; j < 8; ++j) acc[i][j] = -INFINITY;

    const float* xp = xt + (size_t)(bz * KT) * BB + r0 + rg * 8;
    const float* wp = w + (size_t)(bz * KT) * NW + c0w + cg * 4;

    if (is_ero) {
        // acc = max_f (w[f][c] - x[r][f])
#pragma unroll 2
        for (int ff = 0; ff < KT; ff += 2) {
            const float4 xa0 = *(const float4*)(xp);
            const float4 xb0 = *(const float4*)(xp + 4);
            const float4 xa1 = *(const float4*)(xp + BB);
            const float4 xb1 = *(const float4*)(xp + BB + 4);
            const float4 wa0 = *(const float4*)(wp);
            const float4 wb0 = *(const float4*)(wp + 64);
            const float4 wa1 = *(const float4*)(wp + NW);
            const float4 wb1 = *(const float4*)(wp + NW + 64);
            xp += 2 * BB; wp += 2 * NW;
            const float xr0[8] = {xa0.x, xa0.y, xa0.z, xa0.w, xb0.x, xb0.y, xb0.z, xb0.w};
            const float xr1[8] = {xa1.x, xa1.y, xa1.z, xa1.w, xb1.x, xb1.y, xb1.z, xb1.w};
            const float wc0[8] = {wa0.x, wa0.y, wa0.z, wa0.w, wb0.x, wb0.y, wb0.z, wb0.w};
            const float wc1[8] = {wa1.x, wa1.y, wa1.z, wa1.w, wb1.x, wb1.y, wb1.z, wb1.w};
#pragma unroll
            for (int i = 0; i < 8; ++i)
#pragma unroll
                for (int j = 0; j < 8; ++j)
                    acc[i][j] = fmaxf(acc[i][j],
                                      fmaxf(wc0[j] - xr0[i], wc1[j] - xr1[i]));
        }
    } else {
        // acc = max_f (x[r][f] + w[f][c])
#pragma unroll 2
        for (int ff = 0; ff < KT; ff += 2) {
            const float4 xa0 = *(const float4*)(xp);
            const float4 xb0 = *(const float4*)(xp + 4);
            const float4 xa1 = *(const float4*)(xp + BB);
            const float4 xb1 = *(const float4*)(xp + BB + 4);
            const float4 wa0 = *(const float4*)(wp);
            const float4 wb0 = *(const float4*)(wp + 64);
            const float4 wa1 = *(const float4*)(wp + NW);
            const float4 wb1 = *(const float4*)(wp + NW + 64);
            xp += 2 * BB; wp += 2 * NW;
            const float xr0[8] = {xa0.x, xa0.y, xa0.z, xa0.w, xb0.x, xb0.y, xb0.z, xb0.w};
            const float xr1[8] = {xa1.x, xa1.y, xa1.z, xa1.w, xb1.x, xb1.y, xb1.z, xb1.w};
            const float wc0[8] = {wa0.x, wa0.y, wa0.z, wa0.w, wb0.x, wb0.y, wb0.z, wb0.w};
            const float wc1[8] = {wa1.x, wa1.y, wa1.z, wa1.w, wb1.x, wb1.y, wb1.z, wb1.w};
#pragma unroll
            for (int i = 0; i < 8; ++i)
#pragma unroll
                for (int j = 0; j < 8; ++j)
                    acc[i][j] = fmaxf(acc[i][j],
                                      fmaxf(xr0[i] + wc0[j], xr1[i] + wc1[j]));
        }
    }

    // ---- bias row f=FF (x contributes 0 in max-form for both operators) ----
    if (bz == KS - 1) {
        const float4 ba = *(const float4*)(w + (size_t)FF * NW + c0w + cg * 4);
        const float4 bb = *(const float4*)(w + (size_t)FF * NW + c0w + 64 + cg * 4);
        const float bc[8] = {ba.x, ba.y, ba.z, ba.w, bb.x, bb.y, bb.z, bb.w};
#pragma unroll
        for (int i = 0; i < 8; ++i)
#pragma unroll
            for (int j = 0; j < 8; ++j) acc[i][j] = fmaxf(acc[i][j], bc[j]);
    }

    // ---- store raw max-form partial plane (combine negates erosion cols) ----
    float* plane = ws + (size_t)bz * (BB * NOUT);
    const int cglob = bx * CT + cg * 4;   // ero -> 0..255, dil -> 256..511
#pragma unroll
    for (int i = 0; i < 8; ++i) {
        const int row = r0 + rg * 8 + i;
        float4 v0, v1;
        v0.x = acc[i][0]; v0.y = acc[i][1]; v0.z = acc[i][2]; v0.w = acc[i][3];
        v1.x = acc[i][4]; v1.y = acc[i][5]; v1.z = acc[i][6]; v1.w = acc[i][7];
        *(float4*)(plane + (size_t)row * NOUT + cglob) = v0;
        *(float4*)(plane + (size_t)row * NOUT + cglob + 64) = v1;
    }
}

// ---- combine KS max-form planes; negate erosion cols at write ----
__global__ __launch_bounds__(256) void trop_combine(
    const float* __restrict__ ws, float* __restrict__ out)
{
    const int i4 = blockIdx.x * 256 + threadIdx.x;   // float4 index over [BB][NOUT/4]
    const float sgn = ((i4 & 127) < 64) ? -1.0f : 1.0f;  // first 64 f4 of each row = ero
    const int stride4 = BB * NOUT / 4;
    float4 v = ((const float4*)ws)[i4];
#pragma unroll
    for (int z = 1; z < KS; ++z) {
        const float4 u = ((const float4*)ws)[(size_t)z * stride4 + i4];
        v.x = fmaxf(v.x, u.x); v.y = fmaxf(v.y, u.y);
        v.z = fmaxf(v.z, u.z); v.w = fmaxf(v.w, u.w);
    }
    v.x *= sgn; v.y *= sgn; v.z *= sgn; v.w *= sgn;
    ((float4*)out)[i4] = v;
}

extern "C" void kernel_launch(void* const* d_in, const int* in_sizes, int n_in,
                              void* d_out, int out_size, void* d_ws, size_t ws_size,
                              hipStream_t stream) {
    const float* x = (const float*)d_in[0];
    const float* dil = (const float*)d_in[1];
    const float* ero = (const float*)d_in[2];
    float* out = (float*)d_out;
    float* ws = (float*)d_ws;
    float* xt = ws + XT_OFF;

    dim3 tgrid(FF / 64, BB / 64);          // 16 x 16
    trop_transpose<<<tgrid, 256, 0, stream>>>(x, xt);

    dim3 grid(4, BB / BT, KS);             // 4 x 8 x 16 = 512 blocks
    trop_main<<<grid, 256, 0, stream>>>(xt, dil, ero, ws);

    trop_combine<<<BB * NOUT / 4 / 256, 256, 0, stream>>>(ws, out);
}

// Round 5
// 95.640 us; speedup vs baseline: 1.0141x; 1.0141x over previous
//
#include <hip/hip_runtime.h>
#include <math.h>

#define BB   1024            // batch rows
#define FF   1024            // real features (row FF of weights = bias row)
#define NOUT 512             // [0,256)=eroded, [256,512)=dilated
#define NW   256             // cols per weight matrix
#define BT   128             // rows per block tile
#define CT   128             // cols per block tile
#define KS   32              // K-split planes
#define KT   (FF / KS)       // 32 f per block
#define XT_OFF ((size_t)KS * BB * NOUT)   // float offset of x^T inside ws (64 MB planes, then 4 MB xt)

// ---- 64x64 tile transpose: x[r][f] -> xt[f][r] (both 1024x1024) ----
__global__ __launch_bounds__(256) void trop_transpose(
    const float* __restrict__ x, float* __restrict__ xt)
{
    __shared__ float t[64][65];
    const int f0 = blockIdx.x * 64;
    const int r0 = blockIdx.y * 64;
    const int tr = threadIdx.x >> 4;    // 0..15
    const int tc = threadIdx.x & 15;    // 0..15
#pragma unroll
    for (int q = 0; q < 4; ++q) {
        const int r = tr + q * 16;
        const float4 v = *(const float4*)(x + (size_t)(r0 + r) * FF + f0 + tc * 4);
        t[r][tc * 4 + 0] = v.x; t[r][tc * 4 + 1] = v.y;
        t[r][tc * 4 + 2] = v.z; t[r][tc * 4 + 3] = v.w;
    }
    __syncthreads();
#pragma unroll
    for (int q = 0; q < 4; ++q) {
        const int f = tr + q * 16;
        float4 v;
        v.x = t[tc * 4 + 0][f]; v.y = t[tc * 4 + 1][f];
        v.z = t[tc * 4 + 2][f]; v.w = t[tc * 4 + 3][f];
        *(float4*)(xt + (size_t)(f0 + f) * BB + r0 + tc * 4) = v;
    }
}

// Block: 256 threads = 16 col-groups (cg=tid&15) x 16 row-groups (rg=tid>>4).
// Thread tile 8 rows x 8 cols. LDS 32 KB/block; 3 blocks/CU; 1024-block grid
// rotates ~4 rounds/CU so staging waves overlap compute waves.
__global__ __launch_bounds__(256, 3) void trop_main(
    const float* __restrict__ xt,     // x^T [FF][BB]
    const float* __restrict__ dil,
    const float* __restrict__ ero,
    float* __restrict__ ws)
{
    const int bx = blockIdx.x;            // 0,1: erosion tiles; 2,3: dilation
    const int by = blockIdx.y;            // 0..7 row tile
    const int bz = blockIdx.z;            // 0..KS-1 f slice
    const bool is_ero = (bx < 2);
    const float* __restrict__ w = is_ero ? ero : dil;
    const int c0w = (bx & 1) * CT;
    const int r0 = by * BT;
    const int fb = bz * KT;

    __shared__ float lds_x[KT][BT];       // natural x^T layout (conflict-free b128)
    __shared__ float lds_w[KT][CT];       // natural w layout

    const int tid = threadIdx.x;
    const int cg = tid & 15;
    const int rg = tid >> 4;

    // ---- stage x^T tile (32 f x 128 r): coalesced global, natural LDS b128 ----
#pragma unroll
    for (int it = 0; it < 4; ++it) {
        const int idx = it * 256 + tid;
        const int f = idx >> 5;           // 0..31
        const int r4 = idx & 31;          // 0..31 (16B chunks along r)
        *(float4*)&lds_x[f][r4 * 4] =
            *(const float4*)(xt + (size_t)(fb + f) * BB + r0 + r4 * 4);
    }
    // ---- stage w tile (32 f x 128 c) ----
#pragma unroll
    for (int it = 0; it < 4; ++it) {
        const int idx = it * 256 + tid;
        const int f = idx >> 5;           // 0..31
        const int c4 = idx & 31;          // 0..31
        *(float4*)&lds_w[f][c4 * 4] =
            *(const float4*)(w + (size_t)(fb + f) * NW + c0w + c4 * 4);
    }
    __syncthreads();

    float acc[8][8];
#pragma unroll
    for (int i = 0; i < 8; ++i)
#pragma unroll
        for (int j = 0; j < 8; ++j) acc[i][j] = -INFINITY;

    // ---- inner loop: 2 f per step for v_max3 fusion ----
#pragma unroll 2
    for (int ff = 0; ff < KT; ff += 2) {
        const float4 xa0 = *(const float4*)&lds_x[ff][rg * 8];        // broadcast
        const float4 xb0 = *(const float4*)&lds_x[ff][rg * 8 + 4];
        const float4 xa1 = *(const float4*)&lds_x[ff + 1][rg * 8];
        const float4 xb1 = *(const float4*)&lds_x[ff + 1][rg * 8 + 4];
        const float4 wa0 = *(const float4*)&lds_w[ff][cg * 4];        // 2-way (free)
        const float4 wb0 = *(const float4*)&lds_w[ff][64 + cg * 4];
        const float4 wa1 = *(const float4*)&lds_w[ff + 1][cg * 4];
        const float4 wb1 = *(const float4*)&lds_w[ff + 1][64 + cg * 4];
        const float xr0[8] = {xa0.x, xa0.y, xa0.z, xa0.w, xb0.x, xb0.y, xb0.z, xb0.w};
        const float xr1[8] = {xa1.x, xa1.y, xa1.z, xa1.w, xb1.x, xb1.y, xb1.z, xb1.w};
        const float wc0[8] = {wa0.x, wa0.y, wa0.z, wa0.w, wb0.x, wb0.y, wb0.z, wb0.w};
        const float wc1[8] = {wa1.x, wa1.y, wa1.z, wa1.w, wb1.x, wb1.y, wb1.z, wb1.w};
        if (is_ero) {
#pragma unroll
            for (int i = 0; i < 8; ++i)
#pragma unroll
                for (int j = 0; j < 8; ++j)
                    acc[i][j] = fmaxf(acc[i][j],
                                      fmaxf(wc0[j] - xr0[i], wc1[j] - xr1[i]));
        } else {
#pragma unroll
            for (int i = 0; i < 8; ++i)
#pragma unroll
                for (int j = 0; j < 8; ++j)
                    acc[i][j] = fmaxf(acc[i][j],
                                      fmaxf(xr0[i] + wc0[j], xr1[i] + wc1[j]));
        }
    }

    // ---- bias row f=FF (x contributes 0 in max-form for both operators) ----
    if (bz == KS - 1) {
        const float4 ba = *(const float4*)(w + (size_t)FF * NW + c0w + cg * 4);
        const float4 bb = *(const float4*)(w + (size_t)FF * NW + c0w + 64 + cg * 4);
        const float bc[8] = {ba.x, ba.y, ba.z, ba.w, bb.x, bb.y, bb.z, bb.w};
#pragma unroll
        for (int i = 0; i < 8; ++i)
#pragma unroll
            for (int j = 0; j < 8; ++j) acc[i][j] = fmaxf(acc[i][j], bc[j]);
    }

    // ---- store raw max-form partial plane (combine negates erosion cols) ----
    float* plane = ws + (size_t)bz * (BB * NOUT);
    const int cglob = bx * CT + cg * 4;   // ero -> 0..255, dil -> 256..511
#pragma unroll
    for (int i = 0; i < 8; ++i) {
        const int row = r0 + rg * 8 + i;
        float4 v0, v1;
        v0.x = acc[i][0]; v0.y = acc[i][1]; v0.z = acc[i][2]; v0.w = acc[i][3];
        v1.x = acc[i][4]; v1.y = acc[i][5]; v1.z = acc[i][6]; v1.w = acc[i][7];
        *(float4*)(plane + (size_t)row * NOUT + cglob) = v0;
        *(float4*)(plane + (size_t)row * NOUT + cglob + 64) = v1;
    }
}

// ---- combine KS max-form planes; negate erosion cols at write ----
__global__ __launch_bounds__(256) void trop_combine(
    const float* __restrict__ ws, float* __restrict__ out)
{
    const int i4 = blockIdx.x * 256 + threadIdx.x;   // float4 index over [BB][NOUT/4]
    const float sgn = ((i4 & 127) < 64) ? -1.0f : 1.0f;  // first 64 f4/row = erosion
    const int stride4 = BB * NOUT / 4;
    float4 v = ((const float4*)ws)[i4];
#pragma unroll 8
    for (int z = 1; z < KS; ++z) {
        const float4 u = ((const float4*)ws)[(size_t)z * stride4 + i4];
        v.x = fmaxf(v.x, u.x); v.y = fmaxf(v.y, u.y);
        v.z = fmaxf(v.z, u.z); v.w = fmaxf(v.w, u.w);
    }
    v.x *= sgn; v.y *= sgn; v.z *= sgn; v.w *= sgn;
    ((float4*)out)[i4] = v;
}

extern "C" void kernel_launch(void* const* d_in, const int* in_sizes, int n_in,
                              void* d_out, int out_size, void* d_ws, size_t ws_size,
                              hipStream_t stream) {
    const float* x = (const float*)d_in[0];
    const float* dil = (const float*)d_in[1];
    const float* ero = (const float*)d_in[2];
    float* out = (float*)d_out;
    float* ws = (float*)d_ws;
    float* xt = ws + XT_OFF;

    dim3 tgrid(FF / 64, BB / 64);          // 16 x 16
    trop_transpose<<<tgrid, 256, 0, stream>>>(x, xt);

    dim3 grid(4, BB / BT, KS);             // 4 x 8 x 32 = 1024 blocks
    trop_main<<<grid, 256, 0, stream>>>(xt, dil, ero, ws);

    trop_combine<<<BB * NOUT / 4 / 256, 256, 0, stream>>>(ws, out);
}